// Round 1
// baseline (351.123 us; speedup 1.0000x reference)
//
#include <hip/hip_runtime.h>
#include <hip/hip_bf16.h>

typedef __hip_bfloat16 bf16;
typedef __attribute__((ext_vector_type(8))) short bf16x8;
typedef __attribute__((ext_vector_type(4))) float f32x4;

#define EMB 1024
#define HEADS 16
#define DKV 64
#define SQL 2048
#define SKVL 1024

__device__ __forceinline__ f32x4 mfma16(bf16x8 a, bf16x8 b, f32x4 c) {
  return __builtin_amdgcn_mfma_f32_16x16x32_bf16(a, b, c, 0, 0, 0);
}

__device__ __forceinline__ void gload16(const void* g, void* l) {
  __builtin_amdgcn_global_load_lds((const __attribute__((address_space(1))) void*)g,
                                   (__attribute__((address_space(3))) void*)l,
                                   16, 0, 0);
}

__device__ __forceinline__ short to_bf16s(float f) {
  bf16 h = __float2bfloat16(f);
  return *reinterpret_cast<short*>(&h);
}

// ---------------- conversion kernels ----------------
__global__ __launch_bounds__(256) void k_conv(const float* __restrict__ src,
                                              bf16* __restrict__ dst, int n4) {
  int i = blockIdx.x * 256 + threadIdx.x;
  if (i >= n4) return;
  float4 v = reinterpret_cast<const float4*>(src)[i];
  short4 o;
  o.x = to_bf16s(v.x); o.y = to_bf16s(v.y); o.z = to_bf16s(v.z); o.w = to_bf16s(v.w);
  reinterpret_cast<short4*>(dst)[i] = o;
}

// x_k_v [4,2048,1024] -> first 1024 rows of each batch, bf16 [4096,1024]
__global__ __launch_bounds__(256) void k_conv_slice(const float* __restrict__ src,
                                                    bf16* __restrict__ dst) {
  int i = blockIdx.x * 256 + threadIdx.x;   // quad index [0, 1048576)
  int row = i >> 8;                         // 256 quads per 1024-row
  int c4 = i & 255;
  int b = row >> 10, s = row & 1023;
  float4 v = reinterpret_cast<const float4*>(src)[((b << 11) + s) * 256 + c4];
  short4 o;
  o.x = to_bf16s(v.x); o.y = to_bf16s(v.y); o.z = to_bf16s(v.z); o.w = to_bf16s(v.w);
  reinterpret_cast<short4*>(dst)[i] = o;
}

// mask int32 -> bitmask, bit=1 means MASKED OUT (-1e9)
__global__ __launch_bounds__(256) void k_pack(const int* __restrict__ m,
                                              unsigned* __restrict__ out) {
  int i = blockIdx.x * 256 + threadIdx.x;
  unsigned long long bm = __ballot(m[i] != 0);
  int lane = threadIdx.x & 63;
  if ((lane & 31) == 0) out[i >> 5] = (unsigned)(bm >> (lane & 32));
}

// ---------------- projection GEMM: C = A @ W^T + bias ----------------
// MODE 0: Q -> [B,H,SQ,64] bf16, scaled by 0.125
// MODE 1: K -> [B,H,1024,64] bf16
// MODE 2: V -> [B,H,64,1024] bf16 (transposed; computed as W@A^T for coalesced writes)
template<int MODE>
__global__ __launch_bounds__(256) void k_gemm(const bf16* __restrict__ A,
                                              const bf16* __restrict__ W,
                                              const float* __restrict__ bias,
                                              bf16* __restrict__ out) {
  __shared__ __align__(16) bf16 As[128 * 32];
  __shared__ __align__(16) bf16 Bs[128 * 32];
  const int tid = threadIdx.x;
  const int lane = tid & 63;
  const int wid = tid >> 6;
  const int wm = wid >> 1, wn = wid & 1;
  const int bm = blockIdx.x * 128;
  const int bn = blockIdx.y * 128;

  f32x4 acc[4][4] = {};

  // staging: tile is 128 rows x 32 k of bf16 (64 B/row); 2 chunks of (256thr x 16B)
  const int r0 = wid * 16 + (lane >> 2);
  const int ke = (lane & 3) * 8;
  const bf16* a0 = A + (long)(bm + r0) * EMB + ke;
  const bf16* a1 = a0 + 64 * EMB;
  const bf16* w0 = W + (long)(bn + r0) * EMB + ke;
  const bf16* w1 = w0 + 64 * EMB;
  char* lA0 = (char*)As + wid * 1024;
  char* lA1 = (char*)As + (4 + wid) * 1024;
  char* lB0 = (char*)Bs + wid * 1024;
  char* lB1 = (char*)Bs + (4 + wid) * 1024;

  const int frow = lane & 15;
  const int fkb = (lane >> 4) * 16;   // byte offset in 64-B row
  const char* pa = (const char*)As + (wm * 64 + frow) * 64 + fkb;
  const char* pb = (const char*)Bs + (wn * 64 + frow) * 64 + fkb;

  for (int k0 = 0; k0 < EMB; k0 += 32) {
    __syncthreads();
    gload16(a0 + k0, lA0);
    gload16(a1 + k0, lA1);
    gload16(w0 + k0, lB0);
    gload16(w1 + k0, lB1);
    __syncthreads();
    bf16x8 af[4], bfr[4];
#pragma unroll
    for (int i = 0; i < 4; ++i) af[i] = *(const bf16x8*)(pa + i * 16 * 64);
#pragma unroll
    for (int j = 0; j < 4; ++j) bfr[j] = *(const bf16x8*)(pb + j * 16 * 64);
#pragma unroll
    for (int i = 0; i < 4; ++i)
#pragma unroll
      for (int j = 0; j < 4; ++j)
        acc[i][j] = (MODE == 2) ? mfma16(bfr[j], af[i], acc[i][j])
                                : mfma16(af[i], bfr[j], acc[i][j]);
  }

  const int g4 = (lane >> 4) * 4;
#pragma unroll
  for (int i = 0; i < 4; ++i)
#pragma unroll
    for (int j = 0; j < 4; ++j)
#pragma unroll
      for (int r = 0; r < 4; ++r) {
        if (MODE != 2) {
          int mrow = bm + wm * 64 + i * 16 + g4 + r;
          int ncol = bn + wn * 64 + j * 16 + frow;
          float v = acc[i][j][r] + bias[ncol];
          int hh = ncol >> 6, d = ncol & 63;
          long idx;
          if (MODE == 0) {
            v *= 0.125f;  // fold 1/sqrt(DK) into Q
            int b = mrow >> 11, s = mrow & 2047;
            idx = ((long)(b * HEADS + hh) * SQL + s) * DKV + d;
          } else {
            int b = mrow >> 10, s = mrow & 1023;
            idx = ((long)(b * HEADS + hh) * SKVL + s) * DKV + d;
          }
          out[idx] = __float2bfloat16(v);
        } else {
          int nrow = bn + wn * 64 + j * 16 + g4 + r;   // output channel (h,d)
          int mcol = bm + wm * 64 + i * 16 + frow;     // kv position
          float v = acc[i][j][r] + bias[nrow];
          int hh = nrow >> 6, d = nrow & 63;
          int b = mcol >> 10, s = mcol & 1023;
          long idx = ((long)(b * HEADS + hh) * DKV + d) * SKVL + s;
          out[idx] = __float2bfloat16(v);
        }
      }
}

// ---------------- fused masked flash attention ----------------
// grid: (SQ/64, B*H). 4 waves/block, each wave owns 16 q-rows. KV tile = 64.
__global__ __launch_bounds__(256) void k_attn(const bf16* __restrict__ Q,
                                              const bf16* __restrict__ Kc,
                                              const bf16* __restrict__ Vt,
                                              const unsigned* __restrict__ mp,
                                              float* __restrict__ out) {
  __shared__ __align__(16) bf16 Ks[64 * 64];      // [kv][dk], XOR-swizzled rows
  __shared__ __align__(16) bf16 Vs[64 * 64];      // V^T tile [dv][kv], swizzled
  __shared__ __align__(16) bf16 Ps[4][16 * 64];   // per-wave P, swizzled
  const int tid = threadIdx.x, lane = tid & 63, wid = tid >> 6;
  const int bh = blockIdx.y;
  const int b = bh >> 4, h = bh & 15;
  const int qw = blockIdx.x * 64 + wid * 16;

  const int frow = lane & 15;
  const int fkb = (lane >> 4) * 16;
  const int g4 = (lane >> 4) * 4;

  // Q fragment (held in regs for whole kernel); Q is pre-scaled by 0.125
  const bf16* qp = Q + ((long)bh * SQL + qw + frow) * DKV + (lane >> 4) * 8;
  bf16x8 qf0 = *(const bf16x8*)qp;
  bf16x8 qf1 = *(const bf16x8*)(qp + 32);

  // staging addrs: LDS linear dest, global source pre-XOR-swizzled (rule #21)
  const int srow = tid >> 3;                                   // 0..31
  const int sinn = ((tid & 7) * 16) ^ ((srow & 7) << 4);
  const char* kgb = (const char*)Kc + ((long)bh * SKVL + srow) * 128 + sinn;
  const char* vgb = (const char*)Vt + ((long)bh * DKV + srow) * 2048 + sinn;
  char* lK0 = (char*)Ks + wid * 1024;
  char* lK1 = (char*)Ks + (4 + wid) * 1024;
  char* lV0 = (char*)Vs + wid * 1024;
  char* lV1 = (char*)Vs + (4 + wid) * 1024;

  f32x4 zacc[4] = {};
  float mrow[4] = {-3e38f, -3e38f, -3e38f, -3e38f};
  float lrow[4] = {0.f, 0.f, 0.f, 0.f};

  for (int t = 0; t < 16; ++t) {
    __syncthreads();
    gload16(kgb + (long)t * 8192, lK0);
    gload16(kgb + (long)t * 8192 + 32 * 128, lK1);
    gload16(vgb + t * 128, lV0);
    gload16(vgb + t * 128 + 32 * 2048, lV1);
    __syncthreads();

    // S = Q @ K^T  (C layout: col kv = lane&15 within nj-block, row q = g4+r)
    f32x4 s[4];
#pragma unroll
    for (int nj = 0; nj < 4; ++nj) {
      int krow = nj * 16 + frow;
      const char* kb = (const char*)Ks + krow * 128;
      int sw = (krow & 7) << 4;
      bf16x8 kf0 = *(const bf16x8*)(kb + (fkb ^ sw));
      bf16x8 kf1 = *(const bf16x8*)(kb + ((64 + fkb) ^ sw));
      f32x4 sa = {};
      sa = mfma16(qf0, kf0, sa);
      sa = mfma16(qf1, kf1, sa);
      s[nj] = sa;
    }

    // mask: bit=1 -> -1e9 (matches jnp.where(mask, -1e9, s))
    unsigned mw0[4], mw1[4];
#pragma unroll
    for (int r = 0; r < 4; ++r) {
      long mi = ((long)b * SQL + qw + g4 + r) * 32 + t * 2;
      mw0[r] = mp[mi];
      mw1[r] = mp[mi + 1];
    }
#pragma unroll
    for (int nj = 0; nj < 4; ++nj) {
      int bit = ((nj & 1) << 4) + frow;
#pragma unroll
      for (int r = 0; r < 4; ++r) {
        unsigned wmask = (nj < 2) ? mw0[r] : mw1[r];
        if ((wmask >> bit) & 1u) s[nj][r] = -1e9f;
      }
    }

    // online softmax
    float pr[4][4];
#pragma unroll
    for (int r = 0; r < 4; ++r) {
      float mx = fmaxf(fmaxf(s[0][r], s[1][r]), fmaxf(s[2][r], s[3][r]));
#pragma unroll
      for (int d = 1; d < 16; d <<= 1) mx = fmaxf(mx, __shfl_xor(mx, d));
      float mnew = fmaxf(mrow[r], mx);
      float sc = __expf(mrow[r] - mnew);
      mrow[r] = mnew;
      float ps = 0.f;
#pragma unroll
      for (int nj = 0; nj < 4; ++nj) {
        float e = __expf(s[nj][r] - mnew);
        pr[nj][r] = e;
        ps += e;
      }
#pragma unroll
      for (int d = 1; d < 16; d <<= 1) ps += __shfl_xor(ps, d);
      lrow[r] = lrow[r] * sc + ps;
#pragma unroll
      for (int nj = 0; nj < 4; ++nj) zacc[nj][r] *= sc;
    }

    // P -> LDS (per-wave buffer), swizzled rows
    char* pw = (char*)Ps[wid];
#pragma unroll
    for (int r = 0; r < 4; ++r) {
      int prow = g4 + r;
      int swp = (prow & 7) << 4;
#pragma unroll
      for (int nj = 0; nj < 4; ++nj) {
        int cb = ((nj * 16 + frow) * 2) ^ swp;
        *(short*)(pw + prow * 128 + cb) = to_bf16s(pr[nj][r]);
      }
    }
    __syncthreads();

    // Z += P @ V
    const char* pp = (const char*)Ps[wid] + frow * 128;
    int swr = (frow & 7) << 4;
    bf16x8 pf0 = *(const bf16x8*)(pp + (fkb ^ swr));
    bf16x8 pf1 = *(const bf16x8*)(pp + ((64 + fkb) ^ swr));
#pragma unroll
    for (int nj = 0; nj < 4; ++nj) {
      int vrow = nj * 16 + frow;
      const char* vb = (const char*)Vs + vrow * 128;
      int swv = (vrow & 7) << 4;
      bf16x8 vf0 = *(const bf16x8*)(vb + (fkb ^ swv));
      bf16x8 vf1 = *(const bf16x8*)(vb + ((64 + fkb) ^ swv));
      zacc[nj] = mfma16(pf0, vf0, zacc[nj]);
      zacc[nj] = mfma16(pf1, vf1, zacc[nj]);
    }
  }

  // epilogue: out[b, q, h*64+dv] = z / l   (fp32)
#pragma unroll
  for (int r = 0; r < 4; ++r) {
    float inv = 1.0f / lrow[r];
    int q = qw + g4 + r;
#pragma unroll
    for (int nj = 0; nj < 4; ++nj) {
      long idx = ((long)b * SQL + q) * (HEADS * DKV) + h * DKV + nj * 16 + frow;
      out[idx] = zacc[nj][r] * inv;
    }
  }
}

extern "C" void kernel_launch(void* const* d_in, const int* in_sizes, int n_in,
                              void* d_out, int out_size, void* d_ws, size_t ws_size,
                              hipStream_t stream) {
  const float* x_q = (const float*)d_in[0];
  const float* x_kv = (const float*)d_in[1];
  const int* mask = (const int*)d_in[2];
  const float* wqw = (const float*)d_in[3];
  const float* wqb = (const float*)d_in[4];
  const float* wkw = (const float*)d_in[5];
  const float* wkb = (const float*)d_in[6];
  const float* wvw = (const float*)d_in[7];
  const float* wvb = (const float*)d_in[8];
  float* out = (float*)d_out;

  char* w = (char*)d_ws;                       // 63 MB used
  bf16* xq_b  = (bf16*)(w);                    // [8192,1024]  16 MB
  bf16* xkv_b = (bf16*)(w + (16l << 20));      // [4096,1024]   8 MB
  bf16* wq_b  = (bf16*)(w + (24l << 20));      // [1024,1024]   2 MB
  bf16* wk_b  = (bf16*)(w + (26l << 20));
  bf16* wv_b  = (bf16*)(w + (28l << 20));
  bf16* Qb    = (bf16*)(w + (30l << 20));      // [B,H,SQ,64]  16 MB (pre-scaled)
  bf16* Kb    = (bf16*)(w + (46l << 20));      // [B,H,1024,64] 8 MB
  bf16* Vtb   = (bf16*)(w + (54l << 20));      // [B,H,64,1024] 8 MB
  unsigned* mpk = (unsigned*)(w + (62l << 20));// [B,SQ,32]     1 MB

  k_conv<<<8192, 256, 0, stream>>>(x_q, xq_b, 2097152);
  k_conv_slice<<<4096, 256, 0, stream>>>(x_kv, xkv_b);
  k_conv<<<1024, 256, 0, stream>>>(wqw, wq_b, 262144);
  k_conv<<<1024, 256, 0, stream>>>(wkw, wk_b, 262144);
  k_conv<<<1024, 256, 0, stream>>>(wvw, wv_b, 262144);
  k_pack<<<32768, 256, 0, stream>>>(mask, mpk);
  k_gemm<0><<<dim3(64, 8), 256, 0, stream>>>(xq_b, wq_b, wqb, Qb);
  k_gemm<1><<<dim3(32, 8), 256, 0, stream>>>(xkv_b, wk_b, wkb, Kb);
  k_gemm<2><<<dim3(32, 8), 256, 0, stream>>>(xkv_b, wv_b, wvb, Vtb);
  k_attn<<<dim3(32, 64), 256, 0, stream>>>(Qb, Kb, Vtb, mpk, out);
}

// Round 4
// 273.969 us; speedup vs baseline: 1.2816x; 1.2816x over previous
//
#include <hip/hip_runtime.h>
#include <hip/hip_bf16.h>

typedef __hip_bfloat16 bf16;
typedef __attribute__((ext_vector_type(8))) short bf16x8;
typedef __attribute__((ext_vector_type(4))) float f32x4;

#define EMB 1024
#define HEADS 16
#define DKV 64
#define SQL 2048
#define SKVL 1024

// Q scale: 1/sqrt(64) * log2(e)  (softmax runs in exp2 domain)
#define QSCALE 0.1803368801111204f

__device__ __forceinline__ f32x4 mfma16(bf16x8 a, bf16x8 b, f32x4 c) {
  return __builtin_amdgcn_mfma_f32_16x16x32_bf16(a, b, c, 0, 0, 0);
}

__device__ __forceinline__ void gload16(const void* g, void* l) {
  __builtin_amdgcn_global_load_lds((const __attribute__((address_space(1))) void*)g,
                                   (__attribute__((address_space(3))) void*)l,
                                   16, 0, 0);
}

__device__ __forceinline__ short to_bf16s(float f) {
  bf16 h = __float2bfloat16(f);
  return *reinterpret_cast<short*>(&h);
}

// ---------------- merged conversion kernel ----------------
__device__ __forceinline__ void cvt_store(bf16* dst, int i, float4 v) {
  short4 o;
  o.x = to_bf16s(v.x); o.y = to_bf16s(v.y); o.z = to_bf16s(v.z); o.w = to_bf16s(v.w);
  reinterpret_cast<short4*>(dst)[i] = o;
}

__global__ __launch_bounds__(256) void k_convall(
    const float* __restrict__ xq, const float* __restrict__ xkv,
    const float* __restrict__ wq, const float* __restrict__ wk,
    const float* __restrict__ wv,
    bf16* __restrict__ xq_b, bf16* __restrict__ xkv_b,
    bf16* __restrict__ wq_b, bf16* __restrict__ wk_b, bf16* __restrict__ wv_b) {
  int i = blockIdx.x * 256 + threadIdx.x;
  if (i < 2097152) {
    cvt_store(xq_b, i, reinterpret_cast<const float4*>(xq)[i]);
  } else if (i < 3145728) {
    int j = i - 2097152;
    int row = j >> 8, c4 = j & 255;
    int b = row >> 10, s = row & 1023;
    cvt_store(xkv_b, j, reinterpret_cast<const float4*>(xkv)[((b << 11) + s) * 256 + c4]);
  } else if (i < 3407872) {
    int j = i - 3145728;
    cvt_store(wq_b, j, reinterpret_cast<const float4*>(wq)[j]);
  } else if (i < 3670016) {
    int j = i - 3407872;
    cvt_store(wk_b, j, reinterpret_cast<const float4*>(wk)[j]);
  } else {
    int j = i - 3670016;
    cvt_store(wv_b, j, reinterpret_cast<const float4*>(wv)[j]);
  }
}

// mask int32 -> bitmask, bit=1 means MASKED OUT (-1e9)
__global__ __launch_bounds__(256) void k_pack(const int* __restrict__ m,
                                              unsigned* __restrict__ out) {
  int i = blockIdx.x * 256 + threadIdx.x;
  unsigned long long bm = __ballot(m[i] != 0);
  int lane = threadIdx.x & 63;
  if ((lane & 31) == 0) out[i >> 5] = (unsigned)(bm >> (lane & 32));
}

// ---------------- projection GEMM: C = A @ W^T + bias ----------------
// MODE 0: Q -> [B,H,SQ,64] bf16, scaled by QSCALE
// MODE 1: K -> [B,H,1024,64] bf16
// MODE 2: V -> [B,H,64,1024] bf16 (transposed via swapped MFMA operands)
template<int MODE>
__device__ void gemm_body(const bf16* __restrict__ A, const bf16* __restrict__ W,
                          const float* __restrict__ bias, bf16* __restrict__ out,
                          bf16* As, bf16* Bs) {
  const int tid = threadIdx.x;
  const int lane = tid & 63;
  const int wid = tid >> 6;
  const int wm = wid >> 1, wn = wid & 1;
  const int bm = blockIdx.x * 128;
  const int bn = blockIdx.y * 128;

  f32x4 acc[4][4] = {};

  const int r0 = wid * 16 + (lane >> 2);
  const int ke = (lane & 3) * 8;
  const bf16* a0 = A + (long)(bm + r0) * EMB + ke;
  const bf16* a1 = a0 + 64 * EMB;
  const bf16* w0 = W + (long)(bn + r0) * EMB + ke;
  const bf16* w1 = w0 + 64 * EMB;
  char* lA0 = (char*)As + wid * 1024;
  char* lA1 = (char*)As + (4 + wid) * 1024;
  char* lB0 = (char*)Bs + wid * 1024;
  char* lB1 = (char*)Bs + (4 + wid) * 1024;

  const int frow = lane & 15;
  const int fkb = (lane >> 4) * 16;
  const char* pa = (const char*)As + (wm * 64 + frow) * 64 + fkb;
  const char* pb = (const char*)Bs + (wn * 64 + frow) * 64 + fkb;

  for (int k0 = 0; k0 < EMB; k0 += 32) {
    __syncthreads();
    gload16(a0 + k0, lA0);
    gload16(a1 + k0, lA1);
    gload16(w0 + k0, lB0);
    gload16(w1 + k0, lB1);
    __syncthreads();
    bf16x8 af[4], bfr[4];
#pragma unroll
    for (int i = 0; i < 4; ++i) af[i] = *(const bf16x8*)(pa + i * 16 * 64);
#pragma unroll
    for (int j = 0; j < 4; ++j) bfr[j] = *(const bf16x8*)(pb + j * 16 * 64);
#pragma unroll
    for (int i = 0; i < 4; ++i)
#pragma unroll
      for (int j = 0; j < 4; ++j)
        acc[i][j] = (MODE == 2) ? mfma16(bfr[j], af[i], acc[i][j])
                                : mfma16(af[i], bfr[j], acc[i][j]);
  }

  const int g4 = (lane >> 4) * 4;
#pragma unroll
  for (int i = 0; i < 4; ++i)
#pragma unroll
    for (int j = 0; j < 4; ++j)
#pragma unroll
      for (int r = 0; r < 4; ++r) {
        if (MODE != 2) {
          int mrow = bm + wm * 64 + i * 16 + g4 + r;
          int ncol = bn + wn * 64 + j * 16 + frow;
          float v = acc[i][j][r] + bias[ncol];
          int hh = ncol >> 6, d = ncol & 63;
          long idx;
          if (MODE == 0) {
            v *= QSCALE;
            int b = mrow >> 11, s = mrow & 2047;
            idx = ((long)(b * HEADS + hh) * SQL + s) * DKV + d;
          } else {
            int b = mrow >> 10, s = mrow & 1023;
            idx = ((long)(b * HEADS + hh) * SKVL + s) * DKV + d;
          }
          out[idx] = __float2bfloat16(v);
        } else {
          int nrow = bn + wn * 64 + j * 16 + g4 + r;
          int mcol = bm + wm * 64 + i * 16 + frow;
          float v = acc[i][j][r] + bias[nrow];
          int hh = nrow >> 6, d = nrow & 63;
          int b = mcol >> 10, s = mcol & 1023;
          long idx = ((long)(b * HEADS + hh) * DKV + d) * SKVL + s;
          out[idx] = __float2bfloat16(v);
        }
      }
}

__global__ __launch_bounds__(256) void k_gemm3(
    const bf16* __restrict__ xq, const bf16* __restrict__ xkv,
    const bf16* __restrict__ wq, const bf16* __restrict__ wk,
    const bf16* __restrict__ wv,
    const float* __restrict__ bq, const float* __restrict__ bk,
    const float* __restrict__ bv,
    bf16* __restrict__ Qb, bf16* __restrict__ Kb, bf16* __restrict__ Vtb) {
  __shared__ __align__(16) bf16 As[128 * 32];
  __shared__ __align__(16) bf16 Bs[128 * 32];
  int mode = blockIdx.z;
  if (mode == 0) {
    gemm_body<0>(xq, wq, bq, Qb, As, Bs);
  } else if (mode == 1) {
    if (blockIdx.x >= 32) return;
    gemm_body<1>(xkv, wk, bk, Kb, As, Bs);
  } else {
    if (blockIdx.x >= 32) return;
    gemm_body<2>(xkv, wv, bv, Vtb, As, Bs);
  }
}

// ---------------- fused masked flash attention (swapped-QK^T) ----------------
// grid: (SQ/64, B*H). 4 waves/block, wave owns 16 q-rows; KV tile = 64.
// Per lane: q-row = lane&15 for softmax state; kv = nj*16 + g4 + r in S^T.
__global__ __launch_bounds__(256) void k_attn(const bf16* __restrict__ Q,
                                              const bf16* __restrict__ Kc,
                                              const bf16* __restrict__ Vt,
                                              const unsigned* __restrict__ mp,
                                              float* __restrict__ out) {
  __shared__ __align__(16) bf16 Ks[64 * 64];      // [kv][dk], XOR-swizzled rows
  __shared__ __align__(16) bf16 Vs[64 * 64];      // V^T tile [dv][kv], swizzled
  __shared__ __align__(16) bf16 Ps[4][16 * 64];   // per-wave P [q][kv], swizzled
  const int tid = threadIdx.x, lane = tid & 63, wid = tid >> 6;
  const int bh = blockIdx.y;
  const int b = bh >> 4, h = bh & 15;
  const int qw = blockIdx.x * 64 + wid * 16;

  const int frow = lane & 15;
  const int fkb = (lane >> 4) * 16;
  const int g4 = (lane >> 4) * 4;

  // Q fragment (B operand of swapped QK^T); pre-scaled by QSCALE
  const bf16* qp = Q + ((long)bh * SQL + qw + frow) * DKV + (lane >> 4) * 8;
  bf16x8 qf0 = *(const bf16x8*)qp;
  bf16x8 qf1 = *(const bf16x8*)(qp + 32);

  // mask row for q = qw + frow (one uint2 per tile)
  const uint2* mrp = (const uint2*)(mp + ((long)b * SQL + qw + frow) * 32);

  // staging: global source pre-XOR-swizzled, LDS dest linear (rule #21)
  const int srow = tid >> 3;                                   // 0..31
  const int sinn = ((tid & 7) * 16) ^ ((srow & 7) << 4);
  const char* kgb = (const char*)Kc + ((long)bh * SKVL + srow) * 128 + sinn;
  const char* vgb = (const char*)Vt + ((long)bh * DKV + srow) * 2048 + sinn;

  f32x4 zacc[4] = {};
  float mrow = -3e38f;
  float lrow = 0.f;

  // T14 prologue: tile-0 loads into regs
  uint4 kr0 = *(const uint4*)(kgb);
  uint4 kr1 = *(const uint4*)(kgb + 32 * 128);
  uint4 vr0 = *(const uint4*)(vgb);
  uint4 vr1 = *(const uint4*)(vgb + 32 * 2048);

  for (int t = 0; t < 16; ++t) {
    __syncthreads();   // all waves done reading previous tile
    *(uint4*)((char*)Ks + tid * 16) = kr0;
    *(uint4*)((char*)Ks + 4096 + tid * 16) = kr1;
    *(uint4*)((char*)Vs + tid * 16) = vr0;
    *(uint4*)((char*)Vs + 4096 + tid * 16) = vr1;
    __syncthreads();   // tile t visible
    if (t < 15) {      // issue t+1 loads; latency hides under compute(t)
      kr0 = *(const uint4*)(kgb + (long)(t + 1) * 8192);
      kr1 = *(const uint4*)(kgb + (long)(t + 1) * 8192 + 32 * 128);
      vr0 = *(const uint4*)(vgb + (t + 1) * 128);
      vr1 = *(const uint4*)(vgb + (t + 1) * 128 + 32 * 2048);
    }

    // S^T = K @ Q^T : s[nj][r] = S[q=frow][kv = nj*16 + g4 + r]
    f32x4 s[4];
    __builtin_amdgcn_s_setprio(1);
#pragma unroll
    for (int nj = 0; nj < 4; ++nj) {
      int krow = nj * 16 + frow;
      const char* kb = (const char*)Ks + krow * 128;
      int sw = (krow & 7) << 4;
      bf16x8 kf0 = *(const bf16x8*)(kb + (fkb ^ sw));
      bf16x8 kf1 = *(const bf16x8*)(kb + ((64 + fkb) ^ sw));
      f32x4 sa = {};
      sa = mfma16(kf0, qf0, sa);
      sa = mfma16(kf1, qf1, sa);
      s[nj] = sa;
    }
    __builtin_amdgcn_s_setprio(0);

    // mask: bit=1 -> -1e9
    uint2 mw = mrp[t];
#pragma unroll
    for (int nj = 0; nj < 4; ++nj) {
      unsigned wmask = (nj < 2) ? mw.x : mw.y;
#pragma unroll
      for (int r = 0; r < 4; ++r) {
        if ((wmask >> (((nj & 1) << 4) + g4 + r)) & 1u) s[nj][r] = -1e9f;
      }
    }

    // in-lane max over this lane's 16 kv values
    float tm = s[0][0];
#pragma unroll
    for (int nj = 0; nj < 4; ++nj)
#pragma unroll
      for (int r = 0; r < 4; ++r) tm = fmaxf(tm, s[nj][r]);

    // T13 defer-max: only rescale when some row grew past m+8
    if (__any(tm > mrow + 8.0f)) {
      float tmax = fmaxf(tm, __shfl_xor(tm, 16));
      tmax = fmaxf(tmax, __shfl_xor(tmax, 32));
      float mnew = fmaxf(mrow, tmax);
      float sc = __builtin_amdgcn_exp2f(mrow - mnew);
      mrow = mnew;
      lrow *= sc;
      float scq[4];
#pragma unroll
      for (int r = 0; r < 4; ++r) scq[r] = __shfl(sc, g4 + r);
#pragma unroll
      for (int nj = 0; nj < 4; ++nj)
#pragma unroll
        for (int r = 0; r < 4; ++r) zacc[nj][r] *= scq[r];
    }

    // P = exp2(s - m), per-lane partial sum (cross-lane deferred to epilogue)
    float pr[4][4];
    float psum = 0.f;
#pragma unroll
    for (int nj = 0; nj < 4; ++nj)
#pragma unroll
      for (int r = 0; r < 4; ++r) {
        float e = __builtin_amdgcn_exp2f(s[nj][r] - mrow);
        pr[nj][r] = e;
        psum += e;
      }
    lrow += psum;

    // P -> LDS: row q=frow, 4 consecutive kv per nj -> ds_write_b64
    char* pw = (char*)Ps[wid] + frow * 128;
    const int swz = (frow & 7) << 4;
#pragma unroll
    for (int nj = 0; nj < 4; ++nj) {
      short4 pk;
      pk.x = to_bf16s(pr[nj][0]);
      pk.y = to_bf16s(pr[nj][1]);
      pk.z = to_bf16s(pr[nj][2]);
      pk.w = to_bf16s(pr[nj][3]);
      *(short4*)(pw + ((nj * 32 + g4 * 2) ^ swz)) = pk;
    }
    // no barrier: Ps[wid] is wave-private (lgkmcnt ordering suffices)

    // Z += P @ V
    bf16x8 pf0 = *(const bf16x8*)(pw + (fkb ^ swz));
    bf16x8 pf1 = *(const bf16x8*)(pw + ((64 + fkb) ^ swz));
    __builtin_amdgcn_s_setprio(1);
#pragma unroll
    for (int nj = 0; nj < 4; ++nj) {
      int vrow = nj * 16 + frow;
      const char* vb = (const char*)Vs + vrow * 128;
      int swv = (vrow & 7) << 4;
      bf16x8 vf0 = *(const bf16x8*)(vb + (fkb ^ swv));
      bf16x8 vf1 = *(const bf16x8*)(vb + ((64 + fkb) ^ swv));
      zacc[nj] = mfma16(pf0, vf0, zacc[nj]);
      zacc[nj] = mfma16(pf1, vf1, zacc[nj]);
    }
    __builtin_amdgcn_s_setprio(0);
  }

  // finalize l per q-row (4-lane partials), then redistribute to z layout
  lrow += __shfl_xor(lrow, 16);
  lrow += __shfl_xor(lrow, 32);
  float invl = 1.0f / lrow;
  float inv[4];
#pragma unroll
  for (int r = 0; r < 4; ++r) inv[r] = __shfl(invl, g4 + r);

#pragma unroll
  for (int r = 0; r < 4; ++r) {
    int q = qw + g4 + r;
#pragma unroll
    for (int nj = 0; nj < 4; ++nj) {
      long idx = ((long)b * SQL + q) * (HEADS * DKV) + h * DKV + nj * 16 + frow;
      out[idx] = zacc[nj][r] * inv[r];
    }
  }
}

extern "C" void kernel_launch(void* const* d_in, const int* in_sizes, int n_in,
                              void* d_out, int out_size, void* d_ws, size_t ws_size,
                              hipStream_t stream) {
  const float* x_q = (const float*)d_in[0];
  const float* x_kv = (const float*)d_in[1];
  const int* mask = (const int*)d_in[2];
  const float* wqw = (const float*)d_in[3];
  const float* wqb = (const float*)d_in[4];
  const float* wkw = (const float*)d_in[5];
  const float* wkb = (const float*)d_in[6];
  const float* wvw = (const float*)d_in[7];
  const float* wvb = (const float*)d_in[8];
  float* out = (float*)d_out;

  char* w = (char*)d_ws;
  bf16* xq_b  = (bf16*)(w);                    // [8192,1024]  16 MB
  bf16* xkv_b = (bf16*)(w + (16l << 20));      // [4096,1024]   8 MB
  bf16* wq_b  = (bf16*)(w + (24l << 20));      // [1024,1024]   2 MB
  bf16* wk_b  = (bf16*)(w + (26l << 20));
  bf16* wv_b  = (bf16*)(w + (28l << 20));
  bf16* Qb    = (bf16*)(w + (30l << 20));      // [B,H,SQ,64]  16 MB (pre-scaled)
  bf16* Kb    = (bf16*)(w + (46l << 20));      // [B,H,1024,64] 8 MB
  bf16* Vtb   = (bf16*)(w + (54l << 20));      // [B,H,64,1024] 8 MB
  unsigned* mpk = (unsigned*)(w + (62l << 20));// [B,SQ,32]     1 MB

  k_convall<<<15360, 256, 0, stream>>>(x_q, x_kv, wqw, wkw, wvw,
                                       xq_b, xkv_b, wq_b, wk_b, wv_b);
  k_pack<<<32768, 256, 0, stream>>>(mask, mpk);
  k_gemm3<<<dim3(64, 8, 3), 256, 0, stream>>>(xq_b, xkv_b, wq_b, wk_b, wv_b,
                                              wqb, wkb, wvb, Qb, Kb, Vtb);
  k_attn<<<dim3(32, 64), 256, 0, stream>>>(Qb, Kb, Vtb, mpk, out);
}

// Round 8
// 265.061 us; speedup vs baseline: 1.3247x; 1.0336x over previous
//
#include <hip/hip_runtime.h>
#include <hip/hip_bf16.h>

typedef __hip_bfloat16 bf16;
typedef __attribute__((ext_vector_type(8))) short bf16x8;
typedef __attribute__((ext_vector_type(4))) float f32x4;
typedef __attribute__((ext_vector_type(16))) float f32x16;

#define EMB 1024
#define HEADS 16
#define DKV 64
#define SQL 2048
#define SKVL 1024

// Q scale: 1/sqrt(64) * log2(e)  (softmax runs in exp2 domain)
#define QSCALE 0.1803368801111204f

__device__ __forceinline__ f32x4 mfma16(bf16x8 a, bf16x8 b, f32x4 c) {
  return __builtin_amdgcn_mfma_f32_16x16x32_bf16(a, b, c, 0, 0, 0);
}
__device__ __forceinline__ f32x16 mfma32(bf16x8 a, bf16x8 b, f32x16 c) {
  return __builtin_amdgcn_mfma_f32_32x32x16_bf16(a, b, c, 0, 0, 0);
}

__device__ __forceinline__ void gload16(const void* g, void* l) {
  __builtin_amdgcn_global_load_lds((const __attribute__((address_space(1))) void*)g,
                                   (__attribute__((address_space(3))) void*)l,
                                   16, 0, 0);
}

__device__ __forceinline__ short to_bf16s(float f) {
  bf16 h = __float2bfloat16(f);
  return *reinterpret_cast<short*>(&h);
}

__device__ __forceinline__ unsigned cvtpk_bf16(float lo, float hi) {
  unsigned r;
  asm("v_cvt_pk_bf16_f32 %0, %1, %2" : "=v"(r) : "v"(lo), "v"(hi));
  return r;
}

// ---------------- merged conversion kernel ----------------
__device__ __forceinline__ void cvt_store(bf16* dst, int i, float4 v) {
  short4 o;
  o.x = to_bf16s(v.x); o.y = to_bf16s(v.y); o.z = to_bf16s(v.z); o.w = to_bf16s(v.w);
  reinterpret_cast<short4*>(dst)[i] = o;
}

__global__ __launch_bounds__(256) void k_convall(
    const float* __restrict__ xq, const float* __restrict__ xkv,
    const float* __restrict__ wq, const float* __restrict__ wk,
    const float* __restrict__ wv,
    bf16* __restrict__ xq_b, bf16* __restrict__ xkv_b,
    bf16* __restrict__ wq_b, bf16* __restrict__ wk_b, bf16* __restrict__ wv_b) {
  int i = blockIdx.x * 256 + threadIdx.x;
  if (i < 2097152) {
    cvt_store(xq_b, i, reinterpret_cast<const float4*>(xq)[i]);
  } else if (i < 3145728) {
    int j = i - 2097152;
    int row = j >> 8, c4 = j & 255;
    int b = row >> 10, s = row & 1023;
    cvt_store(xkv_b, j, reinterpret_cast<const float4*>(xkv)[((b << 11) + s) * 256 + c4]);
  } else if (i < 3407872) {
    int j = i - 3145728;
    cvt_store(wq_b, j, reinterpret_cast<const float4*>(wq)[j]);
  } else if (i < 3670016) {
    int j = i - 3407872;
    cvt_store(wk_b, j, reinterpret_cast<const float4*>(wk)[j]);
  } else {
    int j = i - 3670016;
    cvt_store(wv_b, j, reinterpret_cast<const float4*>(wv)[j]);
  }
}

// mask int32 -> bitmask, bit=1 means MASKED OUT (-1e9)
__global__ __launch_bounds__(256) void k_pack(const int* __restrict__ m,
                                              unsigned* __restrict__ out) {
  int i = blockIdx.x * 256 + threadIdx.x;
  unsigned long long bm = __ballot(m[i] != 0);
  int lane = threadIdx.x & 63;
  if ((lane & 31) == 0) out[i >> 5] = (unsigned)(bm >> (lane & 32));
}

// ---------------- projection GEMM: C = A @ W^T + bias ----------------
template<int MODE>
__device__ void gemm_body(const bf16* __restrict__ A, const bf16* __restrict__ W,
                          const float* __restrict__ bias, bf16* __restrict__ out,
                          bf16* As, bf16* Bs) {
  const int tid = threadIdx.x;
  const int lane = tid & 63;
  const int wid = tid >> 6;
  const int wm = wid >> 1, wn = wid & 1;
  const int bm = blockIdx.x * 128;
  const int bn = blockIdx.y * 128;

  f32x4 acc[4][4] = {};

  const int r0 = wid * 16 + (lane >> 2);
  const int ke = (lane & 3) * 8;
  const bf16* a0 = A + (long)(bm + r0) * EMB + ke;
  const bf16* a1 = a0 + 64 * EMB;
  const bf16* w0 = W + (long)(bn + r0) * EMB + ke;
  const bf16* w1 = w0 + 64 * EMB;
  char* lA0 = (char*)As + wid * 1024;
  char* lA1 = (char*)As + (4 + wid) * 1024;
  char* lB0 = (char*)Bs + wid * 1024;
  char* lB1 = (char*)Bs + (4 + wid) * 1024;

  const int frow = lane & 15;
  const int fkb = (lane >> 4) * 16;
  const char* pa = (const char*)As + (wm * 64 + frow) * 64 + fkb;
  const char* pb = (const char*)Bs + (wn * 64 + frow) * 64 + fkb;

  for (int k0 = 0; k0 < EMB; k0 += 32) {
    __syncthreads();
    gload16(a0 + k0, lA0);
    gload16(a1 + k0, lA1);
    gload16(w0 + k0, lB0);
    gload16(w1 + k0, lB1);
    __syncthreads();
    bf16x8 af[4], bfr[4];
#pragma unroll
    for (int i = 0; i < 4; ++i) af[i] = *(const bf16x8*)(pa + i * 16 * 64);
#pragma unroll
    for (int j = 0; j < 4; ++j) bfr[j] = *(const bf16x8*)(pb + j * 16 * 64);
#pragma unroll
    for (int i = 0; i < 4; ++i)
#pragma unroll
      for (int j = 0; j < 4; ++j)
        acc[i][j] = (MODE == 2) ? mfma16(bfr[j], af[i], acc[i][j])
                                : mfma16(af[i], bfr[j], acc[i][j]);
  }

  const int g4 = (lane >> 4) * 4;
#pragma unroll
  for (int i = 0; i < 4; ++i)
#pragma unroll
    for (int j = 0; j < 4; ++j)
#pragma unroll
      for (int r = 0; r < 4; ++r) {
        if (MODE != 2) {
          int mrow = bm + wm * 64 + i * 16 + g4 + r;
          int ncol = bn + wn * 64 + j * 16 + frow;
          float v = acc[i][j][r] + bias[ncol];
          int hh = ncol >> 6, d = ncol & 63;
          long idx;
          if (MODE == 0) {
            v *= QSCALE;
            int b = mrow >> 11, s = mrow & 2047;
            idx = ((long)(b * HEADS + hh) * SQL + s) * DKV + d;
          } else {
            int b = mrow >> 10, s = mrow & 1023;
            idx = ((long)(b * HEADS + hh) * SKVL + s) * DKV + d;
          }
          out[idx] = __float2bfloat16(v);
        } else {
          int nrow = bn + wn * 64 + j * 16 + g4 + r;
          int mcol = bm + wm * 64 + i * 16 + frow;
          float v = acc[i][j][r] + bias[nrow];
          int hh = nrow >> 6, d = nrow & 63;
          int b = mcol >> 10, s = mcol & 1023;
          long idx = ((long)(b * HEADS + hh) * DKV + d) * SKVL + s;
          out[idx] = __float2bfloat16(v);
        }
      }
}

__global__ __launch_bounds__(256) void k_gemm3(
    const bf16* __restrict__ xq, const bf16* __restrict__ xkv,
    const bf16* __restrict__ wq, const bf16* __restrict__ wk,
    const bf16* __restrict__ wv,
    const float* __restrict__ bq, const float* __restrict__ bk,
    const float* __restrict__ bv,
    bf16* __restrict__ Qb, bf16* __restrict__ Kb, bf16* __restrict__ Vtb) {
  __shared__ __align__(16) bf16 As[128 * 32];
  __shared__ __align__(16) bf16 Bs[128 * 32];
  int mode = blockIdx.z;
  if (mode == 0) {
    gemm_body<0>(xq, wq, bq, Qb, As, Bs);
  } else if (mode == 1) {
    if (blockIdx.x >= 32) return;
    gemm_body<1>(xkv, wk, bk, Kb, As, Bs);
  } else {
    if (blockIdx.x >= 32) return;
    gemm_body<2>(xkv, wv, bv, Vtb, As, Bs);
  }
}

// ---------------- fused masked flash attention (32x32 MFMA, in-reg P) -------
// grid: (SQ/128, B*H). 4 waves/block, wave owns 32 q-rows; KV tile = 64.
// Swapped QK^T: lane owns q = lane&31; kv per acc-reg r: BR(r) + 4*(lane>>5).
// P redistributed to PV A-frags in-register via cvt_pk + permlane32_swap (T12).
__global__ __launch_bounds__(256, 3) void k_attn(const bf16* __restrict__ Q,
                                                 const bf16* __restrict__ Kc,
                                                 const bf16* __restrict__ Vt,
                                                 const unsigned* __restrict__ mp,
                                                 float* __restrict__ out) {
  __shared__ __align__(16) bf16 Ks[64 * 64];   // [kv][dk], XOR-swizzled rows
  __shared__ __align__(16) bf16 Vs[64 * 64];   // V^T tile [dv][kv], swizzled
  const int tid = threadIdx.x, lane = tid & 63, wid = tid >> 6;
  const int bh = blockIdx.y;
  const int b = bh >> 4, hd = bh & 15;
  const int qw = blockIdx.x * 128 + wid * 32;
  const int l31 = lane & 31;
  const int hh = lane >> 5;          // which 32-lane half
  const int q_lane = qw + l31;
  const int swzA = (l31 & 7) << 4;   // frag-read swizzle (row = l31 mod 32)

  // Q fragments: B-operand rows q=l31; k-slice = kt*16 + hh*8 + e
  const char* qrow = (const char*)Q + ((long)bh * SQL + q_lane) * 128 + hh * 16;
  bf16x8 qf[4];
#pragma unroll
  for (int kt = 0; kt < 4; ++kt) qf[kt] = *(const bf16x8*)(qrow + kt * 32);

  // mask row for this lane's q (uint2 per tile)
  const uint2* mrp = (const uint2*)(mp + ((long)b * SQL + q_lane) * 32);

  // staging: global source pre-XOR-swizzled, LDS dest linear (rule #21)
  const int srow = tid >> 3;
  const int sinn = ((tid & 7) * 16) ^ ((srow & 7) << 4);
  const char* kgb = (const char*)Kc + ((long)bh * SKVL + srow) * 128 + sinn;
  const char* vgb = (const char*)Vt + ((long)bh * DKV + srow) * 2048 + sinn;

  f32x16 zacc0 = {}, zacc1 = {};
  float mrow = -3e38f;
  float lrow = 0.f;

  // T14 prologue: tile-0 loads into regs
  uint4 kr0 = *(const uint4*)(kgb);
  uint4 kr1 = *(const uint4*)(kgb + 32 * 128);
  uint4 vr0 = *(const uint4*)(vgb);
  uint4 vr1 = *(const uint4*)(vgb + 32 * 2048);

  const char* KsC = (const char*)Ks;
  const char* VsC = (const char*)Vs;
  const int kb0 = l31 * 128;         // rows 0-31 (kv/dv set0)
  const int kb1 = kb0 + 4096;        // rows 32-63 (set1)

  for (int t = 0; t < 16; ++t) {
    __syncthreads();   // all waves done reading previous tile
    *(uint4*)((char*)Ks + tid * 16) = kr0;
    *(uint4*)((char*)Ks + 4096 + tid * 16) = kr1;
    *(uint4*)((char*)Vs + tid * 16) = vr0;
    *(uint4*)((char*)Vs + 4096 + tid * 16) = vr1;
    __syncthreads();   // tile t visible
    if (t < 15) {      // issue t+1 loads; latency hides under compute(t)
      kr0 = *(const uint4*)(kgb + (long)(t + 1) * 8192);
      kr1 = *(const uint4*)(kgb + (long)(t + 1) * 8192 + 32 * 128);
      vr0 = *(const uint4*)(vgb + (t + 1) * 128);
      vr1 = *(const uint4*)(vgb + (t + 1) * 128 + 32 * 2048);
    }

    // S^T = K @ Q^T : lane owns q=l31; acc reg r -> kv = BR(r)+4*hh (+32 set1)
    f32x16 s0 = {}, s1 = {};
    __builtin_amdgcn_s_setprio(1);
#pragma unroll
    for (int m = 0; m < 4; ++m) {
      int off = (m * 32 + hh * 16) ^ swzA;
      bf16x8 kf0 = *(const bf16x8*)(KsC + kb0 + off);
      bf16x8 kf1 = *(const bf16x8*)(KsC + kb1 + off);
      s0 = mfma32(kf0, qf[m], s0);
      s1 = mfma32(kf1, qf[m], s1);
    }
    __builtin_amdgcn_s_setprio(0);

    // mask: bit=1 -> -1e9.  bit index = BR(r) + 4*hh; pre-shift by 4*hh.
    uint2 mw = mrp[t];
    unsigned w0s = mw.x >> (hh << 2);
    unsigned w1s = mw.y >> (hh << 2);
#pragma unroll
    for (int r = 0; r < 16; ++r) {
      const int BR = (r & 3) + 8 * (r >> 2);
      if ((w0s >> BR) & 1u) s0[r] = -1e9f;
      if ((w1s >> BR) & 1u) s1[r] = -1e9f;
    }

    // in-lane max over this lane's 32 kv values (fmax nest -> v_max3 fusion)
    float tm = fmaxf(s0[0], s1[0]);
#pragma unroll
    for (int r = 1; r < 16; ++r) tm = fmaxf(tm, fmaxf(s0[r], s1[r]));

    // T13 defer-max: only rescale when some row grew past m+8
    if (__any(tm > mrow + 8.0f)) {
      float tmax = fmaxf(tm, __shfl_xor(tm, 32));
      float mnew = fmaxf(mrow, tmax);
      float sc = __builtin_amdgcn_exp2f(mrow - mnew);
      mrow = mnew;
      lrow *= sc;
#pragma unroll
      for (int r = 0; r < 16; ++r) {
        const int BR = (r & 3) + 8 * (r >> 2);
        float scr = __shfl(sc, (BR + 4 * hh) | (lane & 32));
        zacc0[r] *= scr;
        zacc1[r] *= scr;
      }
    }

    // P = exp2(s - m); per-lane partial row-sum (halves merged in epilogue)
    float psA = 0.f, psB = 0.f;
#pragma unroll
    for (int r = 0; r < 16; ++r) {
      float p0 = __builtin_amdgcn_exp2f(s0[r] - mrow);
      float p1 = __builtin_amdgcn_exp2f(s1[r] - mrow);
      s0[r] = p0; s1[r] = p1;
      psA += p0; psB += p1;
    }
    lrow += psA + psB;

    // PV: build A-frags in-register (T12) and accumulate Z
    __builtin_amdgcn_s_setprio(1);
#pragma unroll
    for (int kt = 0; kt < 4; ++kt) {
      // group gA=2kt (k-slot e=0..3), gB=2kt+1 (e=4..7)
      const int gA = 2 * kt, gB = 2 * kt + 1;
      const int bA = 4 * (gA & 3), bB = 4 * (gB & 3);
      float a0f, a1f, a2f, a3f, b0f, b1f, b2f, b3f;
      if (gA < 4) { a0f = s0[bA]; a1f = s0[bA + 1]; a2f = s0[bA + 2]; a3f = s0[bA + 3]; }
      else        { a0f = s1[bA]; a1f = s1[bA + 1]; a2f = s1[bA + 2]; a3f = s1[bA + 3]; }
      if (gB < 4) { b0f = s0[bB]; b1f = s0[bB + 1]; b2f = s0[bB + 2]; b3f = s0[bB + 3]; }
      else        { b0f = s1[bB]; b1f = s1[bB + 1]; b2f = s1[bB + 2]; b3f = s1[bB + 3]; }
      unsigned pa0 = cvtpk_bf16(a0f, a1f);
      unsigned pa1 = cvtpk_bf16(a2f, a3f);
      unsigned pb0 = cvtpk_bf16(b0f, b1f);
      unsigned pb1 = cvtpk_bf16(b2f, b3f);
      // swap upper-half of first with lower-half of second:
      // result: pa0 = frag VGPR0 (k 0,1), pb0 = frag VGPR2 (k 4,5)
      asm("v_permlane32_swap_b32 %0, %1" : "+v"(pa0), "+v"(pb0));
      asm("v_permlane32_swap_b32 %0, %1" : "+v"(pa1), "+v"(pb1));
      uint4 pu = {pa0, pa1, pb0, pb1};
      bf16x8 pfrag = __builtin_bit_cast(bf16x8, pu);
      int off = (kt * 32 + hh * 16) ^ swzA;
      bf16x8 vf0 = *(const bf16x8*)(VsC + kb0 + off);
      bf16x8 vf1 = *(const bf16x8*)(VsC + kb1 + off);
      zacc0 = mfma32(pfrag, vf0, zacc0);
      zacc1 = mfma32(pfrag, vf1, zacc1);
    }
    __builtin_amdgcn_s_setprio(0);
  }

  // epilogue: merge l across halves, normalize, store fp32
  lrow += __shfl_xor(lrow, 32);
  float invl = 1.0f / lrow;
#pragma unroll
  for (int r = 0; r < 16; ++r) {
    const int BR = (r & 3) + 8 * (r >> 2);
    float invr = __shfl(invl, (BR + 4 * hh) | (lane & 32));
    int q = qw + BR + 4 * hh;
    long base = ((long)b * SQL + q) * (HEADS * DKV) + hd * DKV + l31;
    out[base] = zacc0[r] * invr;
    out[base + 32] = zacc1[r] * invr;
  }
}

extern "C" void kernel_launch(void* const* d_in, const int* in_sizes, int n_in,
                              void* d_out, int out_size, void* d_ws, size_t ws_size,
                              hipStream_t stream) {
  const float* x_q = (const float*)d_in[0];
  const float* x_kv = (const float*)d_in[1];
  const int* mask = (const int*)d_in[2];
  const float* wqw = (const float*)d_in[3];
  const float* wqb = (const float*)d_in[4];
  const float* wkw = (const float*)d_in[5];
  const float* wkb = (const float*)d_in[6];
  const float* wvw = (const float*)d_in[7];
  const float* wvb = (const float*)d_in[8];
  float* out = (float*)d_out;

  char* w = (char*)d_ws;
  bf16* xq_b  = (bf16*)(w);                    // [8192,1024]  16 MB
  bf16* xkv_b = (bf16*)(w + (16l << 20));      // [4096,1024]   8 MB
  bf16* wq_b  = (bf16*)(w + (24l << 20));      // [1024,1024]   2 MB
  bf16* wk_b  = (bf16*)(w + (26l << 20));
  bf16* wv_b  = (bf16*)(w + (28l << 20));
  bf16* Qb    = (bf16*)(w + (30l << 20));      // [B,H,SQ,64]  16 MB (pre-scaled)
  bf16* Kb    = (bf16*)(w + (46l << 20));      // [B,H,1024,64] 8 MB
  bf16* Vtb   = (bf16*)(w + (54l << 20));      // [B,H,64,1024] 8 MB
  unsigned* mpk = (unsigned*)(w + (62l << 20));// [B,SQ,32]     1 MB

  k_convall<<<15360, 256, 0, stream>>>(x_q, x_kv, wqw, wkw, wvw,
                                       xq_b, xkv_b, wq_b, wk_b, wv_b);
  k_pack<<<32768, 256, 0, stream>>>(mask, mpk);
  k_gemm3<<<dim3(64, 8, 3), 256, 0, stream>>>(xq_b, xkv_b, wq_b, wk_b, wv_b,
                                              wqb, wkb, wvb, Qb, Kb, Vtb);
  k_attn<<<dim3(16, 64), 256, 0, stream>>>(Qb, Kb, Vtb, mpk, out);
}